// Round 7
// baseline (595.224 us; speedup 1.0000x reference)
//
#include <hip/hip_runtime.h>

typedef __bf16 bf16_t;
typedef __bf16 bf16x8 __attribute__((ext_vector_type(8)));
typedef __bf16 bf16x4 __attribute__((ext_vector_type(4)));
typedef __bf16 bf16x2 __attribute__((ext_vector_type(2)));
typedef float f32x4 __attribute__((ext_vector_type(4)));

#define NB 8
#define SQ 2048
#define SK 2048
#define DD 512

#define BM 128
#define BN 128
#define BK 32
#define LDK 40   // padded LDS row stride (80 B, 16B-aligned rows for b128)

// ------------------------------------------------- logits = (2 q.k - k^2) * log2e/T
// Round-4 proven structure (152.5 us): bf16 hi/lo split GEMM, fp32 accum,
// inline conversion + k^2. BASE-2 domain (pre-scaled by log2e so downstream
// softmax uses single v_exp_f32). No partials -> zero workspace use.
__global__ __launch_bounds__(256, 2) void logits_kernel(
    const float* __restrict__ Q, const float* __restrict__ K,
    const float* __restrict__ tempP, float* __restrict__ logits) {
  __shared__ bf16_t qh[BM][LDK], ql[BM][LDK], kh[BN][LDK], kl[BN][LDK];
  __shared__ float ksred[BN][8];
  const int b = blockIdx.z;
  const int m0 = blockIdx.y * BM;
  const int n0 = blockIdx.x * BN;
  const int tid = threadIdx.x;
  const int lane = tid & 63;
  const int wave = tid >> 6;
  const int wm = (wave >> 1) * 64;
  const int wn = (wave & 1) * 64;
  const int lrow = lane & 15;
  const int quad = lane >> 4;

  const float* Qb = Q + (size_t)b * SQ * DD;
  const float* Kb = K + (size_t)b * SK * DD;

  const int srow = tid >> 3;        // 0..31
  const int scol = (tid & 7) * 4;   // 0,4,...,28

  const float* qbase = Qb + (size_t)(m0 + srow) * DD + scol;
  const float* kbase = Kb + (size_t)(n0 + srow) * DD + scol;

  f32x4 acc[4][4];
#pragma unroll
  for (int i = 0; i < 4; i++)
#pragma unroll
    for (int j = 0; j < 4; j++) acc[i][j] = (f32x4){0.f, 0.f, 0.f, 0.f};

  float kss[4] = {0.f, 0.f, 0.f, 0.f};

  float4 pq[4], pk[4];
#pragma unroll
  for (int i = 0; i < 4; i++) {
    pq[i] = *(const float4*)(qbase + (size_t)i * 32 * DD);
    pk[i] = *(const float4*)(kbase + (size_t)i * 32 * DD);
  }

  for (int k0 = 0; k0 < DD; k0 += BK) {
    __syncthreads();
#pragma unroll
    for (int i = 0; i < 4; i++) {
      const int r = srow + i * 32;
      float4 qv = pq[i], kv = pk[i];
      bf16_t q0 = (bf16_t)qv.x, q1 = (bf16_t)qv.y, q2 = (bf16_t)qv.z, q3 = (bf16_t)qv.w;
      bf16x4 qhv = {q0, q1, q2, q3};
      bf16x4 qlv = {(bf16_t)(qv.x - (float)q0), (bf16_t)(qv.y - (float)q1),
                    (bf16_t)(qv.z - (float)q2), (bf16_t)(qv.w - (float)q3)};
      bf16_t c0 = (bf16_t)kv.x, c1 = (bf16_t)kv.y, c2 = (bf16_t)kv.z, c3 = (bf16_t)kv.w;
      bf16x4 khv = {c0, c1, c2, c3};
      bf16x4 klv = {(bf16_t)(kv.x - (float)c0), (bf16_t)(kv.y - (float)c1),
                    (bf16_t)(kv.z - (float)c2), (bf16_t)(kv.w - (float)c3)};
      *(bf16x4*)&qh[r][scol] = qhv;
      *(bf16x4*)&ql[r][scol] = qlv;
      *(bf16x4*)&kh[r][scol] = khv;
      *(bf16x4*)&kl[r][scol] = klv;
      kss[i] = fmaf(kv.x, kv.x, kss[i]);
      kss[i] = fmaf(kv.y, kv.y, kss[i]);
      kss[i] = fmaf(kv.z, kv.z, kss[i]);
      kss[i] = fmaf(kv.w, kv.w, kss[i]);
    }
    __syncthreads();

    if (k0 + BK < DD) {
#pragma unroll
      for (int i = 0; i < 4; i++) {
        pq[i] = *(const float4*)(qbase + (size_t)i * 32 * DD + (k0 + BK));
        pk[i] = *(const float4*)(kbase + (size_t)i * 32 * DD + (k0 + BK));
      }
    }

    bf16x8 bh[4], bl[4];
#pragma unroll
    for (int ni = 0; ni < 4; ni++) {
      bh[ni] = *(const bf16x8*)&kh[wn + ni * 16 + lrow][quad * 8];
      bl[ni] = *(const bf16x8*)&kl[wn + ni * 16 + lrow][quad * 8];
    }
#pragma unroll
    for (int mi = 0; mi < 4; mi++) {
      bf16x8 ah = *(const bf16x8*)&qh[wm + mi * 16 + lrow][quad * 8];
      bf16x8 al = *(const bf16x8*)&ql[wm + mi * 16 + lrow][quad * 8];
#pragma unroll
      for (int ni = 0; ni < 4; ni++) {
        acc[mi][ni] = __builtin_amdgcn_mfma_f32_16x16x32_bf16(ah, bh[ni], acc[mi][ni], 0, 0, 0);
        acc[mi][ni] = __builtin_amdgcn_mfma_f32_16x16x32_bf16(ah, bl[ni], acc[mi][ni], 0, 0, 0);
        acc[mi][ni] = __builtin_amdgcn_mfma_f32_16x16x32_bf16(al, bh[ni], acc[mi][ni], 0, 0, 0);
      }
    }
  }

#pragma unroll
  for (int i = 0; i < 4; i++) ksred[srow + i * 32][tid & 7] = kss[i];
  __syncthreads();

  // base-2 pre-scale: logits' = (2 q.k - k^2) * log2(e)/T  (q^2 dropped)
  const float invT = 1.4426950408889634f / tempP[0];
  float* Lb = logits + (size_t)b * SQ * SK;
  float ks4[4];
#pragma unroll
  for (int ni = 0; ni < 4; ni++) {
    const float* kr = ksred[wn + ni * 16 + lrow];
    ks4[ni] = ((kr[0] + kr[1]) + (kr[2] + kr[3])) +
              ((kr[4] + kr[5]) + (kr[6] + kr[7]));
  }

#pragma unroll
  for (int mi = 0; mi < 4; mi++) {
#pragma unroll
    for (int r = 0; r < 4; r++) {
      const int row = wm + mi * 16 + quad * 4 + r;
#pragma unroll
      for (int ni = 0; ni < 4; ni++) {
        float sv = (2.0f * acc[mi][ni][r] - ks4[ni]) * invT;
        Lb[(size_t)(m0 + row) * SK + (n0 + wn + ni * 16 + lrow)] = sv;
      }
    }
  }
}

// ------------------------------------------------- fused softmax + O = W @ V
// ZERO-workspace pv. Block = 32 q-rows x all d (single owner of its W rows).
// Pass A: stream the 32x2048 raw panel once, online base-2 (max,sum) per row
//   (two interleaved accumulators to halve the exp2 dependency chain), 16-lane
//   shfl combine -> Msh/Ssh. No partials buffer needed.
// Pass B: chunked GEMM: W chunks (2 x [32][256] bf16, XOR-swizzled, register
//   chunk-ahead prefetch, normalized in place to global as the weights output)
//   x V transposed on the fly per 32-k window via round-0's pair-pack into
//   vwin[512][40] (2-way bank = free), V-register prefetch one window ahead.
// Barriers: plain s_barrier (vwin free) + lgkmcnt-only barrier (LDS ready;
// global prefetches stay in flight). LDS 72.3 KB -> 2 blocks/CU.
#define PM 32
#define CK 256                 // W k-chunk elements
#define CKB 512                // W chunk row bytes
#define NCH (SK / CK)          // 8 chunks
#define LDV 40                 // vwin row stride in bf16 (80 B)

__device__ __forceinline__ unsigned pv_lds(int row, unsigned kb) {
  return (unsigned)row * CKB + (kb ^ (unsigned)((row & 7) << 4));
}

__global__ __launch_bounds__(512, 4) void pv_kernel(
    float* __restrict__ L,               // raw logits in, weights out (in place)
    const float* __restrict__ V,
    float* __restrict__ O) {
  __shared__ __align__(16) unsigned char wlds[2][PM * CKB];  // 2 x 16 KB
  __shared__ __align__(16) bf16_t vwin[DD][LDV];             // 40 KB
  __shared__ float Msh[PM], Ssh[PM];
  const int bid = blockIdx.x;
  const int b = bid & 7;            // XCD affinity: batch b -> XCD b
  const int m0 = (bid >> 3) * PM;
  const int tid = threadIdx.x;

  float* Lb = L + (size_t)b * SQ * SK;
  const float* Vb = V + (size_t)b * SK * DD;

  const int prow = tid >> 4;        // 0..31 (stats + W staging row)
  const int g = tid & 15;
  float* lp = Lb + (size_t)(m0 + prow) * SK;

  // ---- pass A: per-row online base-2 stats over the raw panel
  {
    float ma = -3.0e38f, sa = 0.f, mb2 = -3.0e38f, sb = 0.f;
#pragma unroll 4
    for (int j = 0; j < 32; j += 2) {
      float4 v = *(const float4*)(lp + g * 4 + j * 64);
      float4 u = *(const float4*)(lp + g * 4 + (j + 1) * 64);
      float mv = fmaxf(fmaxf(v.x, v.y), fmaxf(v.z, v.w));
      float mn = fmaxf(ma, mv);
      sa = sa * exp2f(ma - mn) + (exp2f(v.x - mn) + exp2f(v.y - mn)) +
           (exp2f(v.z - mn) + exp2f(v.w - mn));
      ma = mn;
      float mu = fmaxf(fmaxf(u.x, u.y), fmaxf(u.z, u.w));
      float mo = fmaxf(mb2, mu);
      sb = sb * exp2f(mb2 - mo) + (exp2f(u.x - mo) + exp2f(u.y - mo)) +
           (exp2f(u.z - mo) + exp2f(u.w - mo));
      mb2 = mo;
    }
    float m = fmaxf(ma, mb2);
    float s = sa * exp2f(ma - m) + sb * exp2f(mb2 - m);
#pragma unroll
    for (int off = 1; off <= 8; off <<= 1) {
      float mo = __shfl_xor(m, off);
      float so = __shfl_xor(s, off);
      float mm = fmaxf(m, mo);
      s = s * exp2f(m - mm) + so * exp2f(mo - mm);
      m = mm;
    }
    if (g == 0) {
      Msh[prow] = m;
      Ssh[prow] = 1.0f / s;
    }
  }
  __syncthreads();
  const float Mrow = Msh[prow];
  const float invS = Ssh[prow];

  // ---- W chunk stage: normalize (exp2), write weights in place, LDS bf16
  auto stageW = [&](const float4 (&pw)[4], int c1) {
    unsigned char* buf = wlds[c1 & 1];
    const int kbase = c1 * CK;
#pragma unroll
    for (int j = 0; j < 4; j++) {
      const int k = g * 4 + j * 64;
      float4 v = pw[j];
      const float w0 = exp2f(v.x - Mrow) * invS;
      const float w1 = exp2f(v.y - Mrow) * invS;
      const float w2 = exp2f(v.z - Mrow) * invS;
      const float w3 = exp2f(v.w - Mrow) * invS;
      *(float4*)(lp + kbase + k) = make_float4(w0, w1, w2, w3);  // W output
      bf16x4 w4 = {(bf16_t)w0, (bf16_t)w1, (bf16_t)w2, (bf16_t)w3};
      *(bf16x4*)(buf + pv_lds(prow, (unsigned)(k * 2))) = w4;
    }
  };

  // ---- V staging identity: thread (p = kpair, c2 = d-chunk)
  const int p = tid & 15;
  const int c2 = tid >> 4;          // 0..31; d = 4*c2 + 128*j
  const float* vk = Vb + (size_t)(2 * p) * DD + 4 * c2;

  // ---- GEMM identity: wave -> 64-wide d slice
  const int lane = tid & 63;
  const int wave = tid >> 6;
  const int wn = wave * 64;
  const int lrow = lane & 15;
  const int quad = lane >> 4;

  f32x4 acc[2][4];
#pragma unroll
  for (int i = 0; i < 2; i++)
#pragma unroll
    for (int j = 0; j < 4; j++) acc[i][j] = (f32x4){0.f, 0.f, 0.f, 0.f};

  // ---- prologue: stage W chunk 0; pw <- chunk 1 raw; V regs window 0
  {
    float4 p0[4];
#pragma unroll
    for (int j = 0; j < 4; j++) p0[j] = *(const float4*)(lp + g * 4 + j * 64);
    stageW(p0, 0);
  }
  float4 pw[4];
#pragma unroll
  for (int j = 0; j < 4; j++) pw[j] = *(const float4*)(lp + CK + g * 4 + j * 64);

  float4 va[4], vb2[4];
#pragma unroll
  for (int j = 0; j < 4; j++) {
    va[j] = *(const float4*)(vk + 128 * j);
    vb2[j] = *(const float4*)(vk + DD + 128 * j);
  }

  for (int c = 0; c < NCH; c++) {
    const unsigned char* buf = wlds[c & 1];
#pragma unroll
    for (int wloc = 0; wloc < CK / BK; wloc++) {
      const int gw = c * (CK / BK) + wloc;
      __builtin_amdgcn_s_barrier();            // vwin free (prev window consumed)
      // pair-pack V window: vwin[d][2p..2p+1] <- V[k][d], V[k+1][d]
#pragma unroll
      for (int j = 0; j < 4; j++) {
        const int d0 = 4 * c2 + 128 * j;
        float4 a0 = va[j], a1 = vb2[j];
        bf16x2 t0 = {(bf16_t)a0.x, (bf16_t)a1.x};
        bf16x2 t1 = {(bf16_t)a0.y, (bf16_t)a1.y};
        bf16x2 t2 = {(bf16_t)a0.z, (bf16_t)a1.z};
        bf16x2 t3 = {(bf16_t)a0.w, (bf16_t)a1.w};
        *(bf16x2*)&vwin[d0 + 0][2 * p] = t0;
        *(bf16x2*)&vwin[d0 + 1][2 * p] = t1;
        *(bf16x2*)&vwin[d0 + 2][2 * p] = t2;
        *(bf16x2*)&vwin[d0 + 3][2 * p] = t3;
      }
      // LDS-ready barrier (vwin + any pending W-chunk stage); global loads in flight
      asm volatile("s_waitcnt lgkmcnt(0)\n\ts_barrier" ::: "memory");
      // prefetch next window's V (consumed next iteration)
      if (gw + 1 < SK / BK) {
        const float* vn = vk + (size_t)(gw + 1) * BK * DD;
#pragma unroll
        for (int j = 0; j < 4; j++) {
          va[j] = *(const float4*)(vn + 128 * j);
          vb2[j] = *(const float4*)(vn + DD + 128 * j);
        }
      }
      // GEMM this window
      bf16x8 bb[4];
#pragma unroll
      for (int ni = 0; ni < 4; ni++)
        bb[ni] = *(const bf16x8*)&vwin[wn + ni * 16 + lrow][quad * 8];
      bf16x8 a0 = *(const bf16x8*)(buf + pv_lds(lrow, (unsigned)(wloc * 64 + quad * 16)));
      bf16x8 a1 = *(const bf16x8*)(buf + pv_lds(16 + lrow, (unsigned)(wloc * 64 + quad * 16)));
#pragma unroll
      for (int ni = 0; ni < 4; ni++)
        acc[0][ni] = __builtin_amdgcn_mfma_f32_16x16x32_bf16(a0, bb[ni], acc[0][ni], 0, 0, 0);
#pragma unroll
      for (int ni = 0; ni < 4; ni++)
        acc[1][ni] = __builtin_amdgcn_mfma_f32_16x16x32_bf16(a1, bb[ni], acc[1][ni], 0, 0, 0);
    }
    // chunk boundary: stage W chunk c+1 (ds-writes sync at next lgkm barrier),
    // then issue chunk c+2 raw loads (8 windows of latency cover)
    if (c + 1 < NCH) {
      stageW(pw, c + 1);
      if (c + 2 < NCH) {
        const int kbase = (c + 2) * CK;
#pragma unroll
        for (int j = 0; j < 4; j++)
          pw[j] = *(const float4*)(lp + kbase + g * 4 + j * 64);
      }
    }
  }

  float* Ob = O + (size_t)b * SQ * DD;
#pragma unroll
  for (int ni = 0; ni < 4; ni++) {
    const int d = wn + ni * 16 + lrow;
#pragma unroll
    for (int mi = 0; mi < 2; mi++) {
      const int mbase = m0 + mi * 16 + quad * 4;
#pragma unroll
      for (int r = 0; r < 4; r++) {
        Ob[(size_t)(mbase + r) * DD + d] = acc[mi][ni][r];
      }
    }
  }
}

extern "C" void kernel_launch(void* const* d_in, const int* in_sizes, int n_in,
                              void* d_out, int out_size, void* d_ws, size_t ws_size,
                              hipStream_t stream) {
  const float* Q = (const float*)d_in[0];
  const float* K = (const float*)d_in[1];
  const float* V = (const float*)d_in[2];
  const float* T = (const float*)d_in[3];

  float* outv = (float*)d_out;                          // [8,2048,512]
  float* logits = outv + (size_t)NB * SQ * DD;          // [8,2048,2048] weights region

  // ZERO workspace usage (d_ws untouched) — tests the re-poison-gap hypothesis.
  logits_kernel<<<dim3(SK / BN, SQ / BM, NB), 256, 0, stream>>>(Q, K, T, logits);
  pv_kernel<<<dim3(NB * (SQ / PM)), 512, 0, stream>>>(logits, V, outv);
}

// Round 8
// 489.618 us; speedup vs baseline: 1.2157x; 1.2157x over previous
//
#include <hip/hip_runtime.h>

typedef __bf16 bf16_t;
typedef __bf16 bf16x8 __attribute__((ext_vector_type(8)));
typedef __bf16 bf16x4 __attribute__((ext_vector_type(4)));
typedef __bf16 bf16x2 __attribute__((ext_vector_type(2)));
typedef float f32x4 __attribute__((ext_vector_type(4)));

#define NB 8
#define SQ 2048
#define SK 2048
#define DD 512

#define BM 128
#define BN 128
#define BK 32
#define LDK 40   // padded LDS row stride (80 B, 16B-aligned rows for b128)
#define NG 32    // softmax groups per row (64 cols each)

// ------------------------------------------------- E = exp2((2 q.k - k^2)*log2e/T - m_grp)
// Round-4 proven GEMM body (152.5 us measured): bf16 hi/lo split, fp32 accum,
// inline conversion + k^2. NEW epilogue: stores E = exp2(sv - m_grp) (the rs
// summands it already computes) instead of raw logits, plus per-(row, 64-col
// group) partials (m, s) written DIRECTLY to global (no LDS combine, no extra
// sync). Downstream pv reconstructs W = E * exp2(m_grp - M)/S.
__global__ __launch_bounds__(256, 2) void logits_kernel(
    const float* __restrict__ Q, const float* __restrict__ K,
    const float* __restrict__ tempP, float* __restrict__ logits,
    float* __restrict__ Mpart, float* __restrict__ Spart) {
  __shared__ bf16_t qh[BM][LDK], ql[BM][LDK], kh[BN][LDK], kl[BN][LDK];
  __shared__ float ksred[BN][8];
  const int b = blockIdx.z;
  const int m0 = blockIdx.y * BM;
  const int n0 = blockIdx.x * BN;
  const int tid = threadIdx.x;
  const int lane = tid & 63;
  const int wave = tid >> 6;
  const int wm = (wave >> 1) * 64;
  const int wn = (wave & 1) * 64;
  const int lrow = lane & 15;
  const int quad = lane >> 4;

  const float* Qb = Q + (size_t)b * SQ * DD;
  const float* Kb = K + (size_t)b * SK * DD;

  const int srow = tid >> 3;        // 0..31
  const int scol = (tid & 7) * 4;   // 0,4,...,28

  const float* qbase = Qb + (size_t)(m0 + srow) * DD + scol;
  const float* kbase = Kb + (size_t)(n0 + srow) * DD + scol;

  f32x4 acc[4][4];
#pragma unroll
  for (int i = 0; i < 4; i++)
#pragma unroll
    for (int j = 0; j < 4; j++) acc[i][j] = (f32x4){0.f, 0.f, 0.f, 0.f};

  float kss[4] = {0.f, 0.f, 0.f, 0.f};

  float4 pq[4], pk[4];
#pragma unroll
  for (int i = 0; i < 4; i++) {
    pq[i] = *(const float4*)(qbase + (size_t)i * 32 * DD);
    pk[i] = *(const float4*)(kbase + (size_t)i * 32 * DD);
  }

  for (int k0 = 0; k0 < DD; k0 += BK) {
    __syncthreads();
#pragma unroll
    for (int i = 0; i < 4; i++) {
      const int r = srow + i * 32;
      float4 qv = pq[i], kv = pk[i];
      bf16_t q0 = (bf16_t)qv.x, q1 = (bf16_t)qv.y, q2 = (bf16_t)qv.z, q3 = (bf16_t)qv.w;
      bf16x4 qhv = {q0, q1, q2, q3};
      bf16x4 qlv = {(bf16_t)(qv.x - (float)q0), (bf16_t)(qv.y - (float)q1),
                    (bf16_t)(qv.z - (float)q2), (bf16_t)(qv.w - (float)q3)};
      bf16_t c0 = (bf16_t)kv.x, c1 = (bf16_t)kv.y, c2 = (bf16_t)kv.z, c3 = (bf16_t)kv.w;
      bf16x4 khv = {c0, c1, c2, c3};
      bf16x4 klv = {(bf16_t)(kv.x - (float)c0), (bf16_t)(kv.y - (float)c1),
                    (bf16_t)(kv.z - (float)c2), (bf16_t)(kv.w - (float)c3)};
      *(bf16x4*)&qh[r][scol] = qhv;
      *(bf16x4*)&ql[r][scol] = qlv;
      *(bf16x4*)&kh[r][scol] = khv;
      *(bf16x4*)&kl[r][scol] = klv;
      kss[i] = fmaf(kv.x, kv.x, kss[i]);
      kss[i] = fmaf(kv.y, kv.y, kss[i]);
      kss[i] = fmaf(kv.z, kv.z, kss[i]);
      kss[i] = fmaf(kv.w, kv.w, kss[i]);
    }
    __syncthreads();

    if (k0 + BK < DD) {
#pragma unroll
      for (int i = 0; i < 4; i++) {
        pq[i] = *(const float4*)(qbase + (size_t)i * 32 * DD + (k0 + BK));
        pk[i] = *(const float4*)(kbase + (size_t)i * 32 * DD + (k0 + BK));
      }
    }

    bf16x8 bh[4], bl[4];
#pragma unroll
    for (int ni = 0; ni < 4; ni++) {
      bh[ni] = *(const bf16x8*)&kh[wn + ni * 16 + lrow][quad * 8];
      bl[ni] = *(const bf16x8*)&kl[wn + ni * 16 + lrow][quad * 8];
    }
#pragma unroll
    for (int mi = 0; mi < 4; mi++) {
      bf16x8 ah = *(const bf16x8*)&qh[wm + mi * 16 + lrow][quad * 8];
      bf16x8 al = *(const bf16x8*)&ql[wm + mi * 16 + lrow][quad * 8];
#pragma unroll
      for (int ni = 0; ni < 4; ni++) {
        acc[mi][ni] = __builtin_amdgcn_mfma_f32_16x16x32_bf16(ah, bh[ni], acc[mi][ni], 0, 0, 0);
        acc[mi][ni] = __builtin_amdgcn_mfma_f32_16x16x32_bf16(ah, bl[ni], acc[mi][ni], 0, 0, 0);
        acc[mi][ni] = __builtin_amdgcn_mfma_f32_16x16x32_bf16(al, bh[ni], acc[mi][ni], 0, 0, 0);
      }
    }
  }

#pragma unroll
  for (int i = 0; i < 4; i++) ksred[srow + i * 32][tid & 7] = kss[i];
  __syncthreads();

  // base-2 pre-scale: sv = (2 q.k - k^2) * log2(e)/T  (q^2 dropped)
  const float invT = 1.4426950408889634f / tempP[0];
  float* Lb = logits + (size_t)b * SQ * SK;
  float ks4[4];
#pragma unroll
  for (int ni = 0; ni < 4; ni++) {
    const float* kr = ksred[wn + ni * 16 + lrow];
    ks4[ni] = ((kr[0] + kr[1]) + (kr[2] + kr[3])) +
              ((kr[4] + kr[5]) + (kr[6] + kr[7]));
  }

  // group id of this wave's 64-col slice
  const size_t gbase = ((size_t)b * NG + blockIdx.x * 2 + (wave & 1)) * SQ + m0;

#pragma unroll
  for (int mi = 0; mi < 4; mi++) {
#pragma unroll
    for (int r = 0; r < 4; r++) {
      const int row = wm + mi * 16 + quad * 4 + r;
      float sv[4];
#pragma unroll
      for (int ni = 0; ni < 4; ni++)
        sv[ni] = (2.0f * acc[mi][ni][r] - ks4[ni]) * invT;
      float rm = fmaxf(fmaxf(sv[0], sv[1]), fmaxf(sv[2], sv[3]));
      rm = fmaxf(rm, __shfl_xor(rm, 1));
      rm = fmaxf(rm, __shfl_xor(rm, 2));
      rm = fmaxf(rm, __shfl_xor(rm, 4));
      rm = fmaxf(rm, __shfl_xor(rm, 8));
      float e[4];
      float rs = 0.f;
#pragma unroll
      for (int ni = 0; ni < 4; ni++) {
        e[ni] = exp2f(sv[ni] - rm);
        rs += e[ni];
        Lb[(size_t)(m0 + row) * SK + (n0 + wn + ni * 16 + lrow)] = e[ni];
      }
      rs += __shfl_xor(rs, 1);
      rs += __shfl_xor(rs, 2);
      rs += __shfl_xor(rs, 4);
      rs += __shfl_xor(rs, 8);
      if (lrow == 0) {
        Mpart[gbase + row] = rm;
        Spart[gbase + row] = rs;
      }
    }
  }
}

// ------------------------------------------------- Vt[b][d][k] bf16 = V^T
__global__ __launch_bounds__(256) void vt_kernel(const float* __restrict__ V,
                                                 bf16_t* __restrict__ Vt) {
  const int b = blockIdx.y;
  const int k0 = blockIdx.x * 32;
  const int tid = threadIdx.x;
  const int p = tid & 15;
  const int c = tid >> 4;
  const float* Vb = V + (size_t)b * SK * DD;
  bf16_t* Vtb = Vt + (size_t)b * DD * SK;
  const int k = k0 + 2 * p;
#pragma unroll
  for (int j = 0; j < 8; j++) {
    const int d0 = 4 * c + 64 * j;
    float4 v0 = *(const float4*)(Vb + (size_t)k * DD + d0);
    float4 v1 = *(const float4*)(Vb + (size_t)(k + 1) * DD + d0);
    bf16x2 t0 = {(bf16_t)v0.x, (bf16_t)v1.x};
    bf16x2 t1 = {(bf16_t)v0.y, (bf16_t)v1.y};
    bf16x2 t2 = {(bf16_t)v0.z, (bf16_t)v1.z};
    bf16x2 t3 = {(bf16_t)v0.w, (bf16_t)v1.w};
    *(bf16x2*)(Vtb + (size_t)(d0 + 0) * SK + k) = t0;
    *(bf16x2*)(Vtb + (size_t)(d0 + 1) * SK + k) = t1;
    *(bf16x2*)(Vtb + (size_t)(d0 + 2) * SK + k) = t2;
    *(bf16x2*)(Vtb + (size_t)(d0 + 3) * SK + k) = t3;
  }
}

// ------------------------------------------------- fused softmax-finish + O = W @ V
// Round-6 proven chunked structure (8 lgkm-only barriers total, depth-2
// chunk register prefetch, static bw0/bw1 B-window parity, Vt from L2).
// NEW: input is E = exp2(l - m_grp); stage multiplies by alpha[row][grp] =
// exp2(m_grp - M)/S (4 KB LDS table) instead of computing exp2 per element.
#define PM 32
#define CK 256                 // W k-chunk elements
#define CKB 512                // W chunk row bytes
#define NCH (SK / CK)          // 8 chunks
#define NWIN (SK / BK)         // 64 k-windows

__device__ __forceinline__ unsigned pv_lds(int row, unsigned kb) {
  return (unsigned)row * CKB + (kb ^ (unsigned)((row & 7) << 4));
}

__global__ __launch_bounds__(512, 4) void pv_kernel(
    float* __restrict__ L,               // E in, weights out (in place)
    const bf16_t* __restrict__ Vt,
    const float* __restrict__ Mpart, const float* __restrict__ Spart,
    float* __restrict__ O) {
  __shared__ __align__(16) unsigned char wlds[2][PM * CKB];  // 2 x 16 KB
  __shared__ float ash[PM][NG];                              // 4 KB alpha table
  __shared__ float Msh[PM], Ssh[PM];
  const int bid = blockIdx.x;
  const int b = bid & 7;            // XCD affinity: batch b -> XCD b
  const int m0 = (bid >> 3) * PM;
  const int tid = threadIdx.x;

  float* Lb = L + (size_t)b * SQ * SK;
  const bf16_t* Vtb = Vt + (size_t)b * DD * SK;

  // ---- combine 32 per-group partials -> (M, 1/S) and alpha table
  const int prow = tid >> 4;        // 0..31
  const int g = tid & 15;
  {
    const size_t o = ((size_t)b * NG + g) * SQ + (m0 + prow);
    const float pm0 = Mpart[o], ps0 = Spart[o];
    const float pm1 = Mpart[o + (size_t)16 * SQ], ps1 = Spart[o + (size_t)16 * SQ];
    float m = fmaxf(pm0, pm1);
    float s = ps0 * exp2f(pm0 - m) + ps1 * exp2f(pm1 - m);
#pragma unroll
    for (int off = 1; off <= 8; off <<= 1) {
      float mo = __shfl_xor(m, off);
      float so = __shfl_xor(s, off);
      float mm = fmaxf(m, mo);
      s = s * exp2f(m - mm) + so * exp2f(mo - mm);
      m = mm;
    }
    if (g == 0) {
      Msh[prow] = m;
      Ssh[prow] = 1.0f / s;
    }
    __syncthreads();
    const float M = Msh[prow];
    const float invS = Ssh[prow];
    ash[prow][g] = exp2f(pm0 - M) * invS;
    ash[prow][g + 16] = exp2f(pm1 - M) * invS;
  }
  __syncthreads();

  float* lp = Lb + (size_t)(m0 + prow) * SK;

  // ---- W chunk stage: w = E * alpha, write weights in place, LDS bf16
  auto stageW = [&](const float4 (&pw)[4], int c1) {
    unsigned char* buf = wlds[c1 & 1];
    const int kbase = c1 * CK;
    float a0 = ash[prow][c1 * 4 + 0];
    float a1 = ash[prow][c1 * 4 + 1];
    float a2 = ash[prow][c1 * 4 + 2];
    float a3 = ash[prow][c1 * 4 + 3];
    const float aj[4] = {a0, a1, a2, a3};
#pragma unroll
    for (int j = 0; j < 4; j++) {
      const int k = g * 4 + j * 64;
      float4 v = pw[j];
      const float w0 = v.x * aj[j];
      const float w1 = v.y * aj[j];
      const float w2 = v.z * aj[j];
      const float w3 = v.w * aj[j];
      *(float4*)(lp + kbase + k) = make_float4(w0, w1, w2, w3);  // W output
      bf16x4 w4 = {(bf16_t)w0, (bf16_t)w1, (bf16_t)w2, (bf16_t)w3};
      *(bf16x4*)(buf + pv_lds(prow, (unsigned)(k * 2))) = w4;
    }
  };

  // ---- GEMM identity: wave -> 64-wide d slice
  const int lane = tid & 63;
  const int wave = tid >> 6;
  const int wn = wave * 64;
  const int lrow = lane & 15;
  const int quad = lane >> 4;

  const bf16_t* Brow[4];
#pragma unroll
  for (int ni = 0; ni < 4; ni++)
    Brow[ni] = Vtb + (size_t)(wn + ni * 16 + lrow) * SK + quad * 8;

  f32x4 acc[2][4];
#pragma unroll
  for (int i = 0; i < 2; i++)
#pragma unroll
    for (int j = 0; j < 4; j++) acc[i][j] = (f32x4){0.f, 0.f, 0.f, 0.f};

  // ---- prologue: stage chunk 0; pA <- chunk 1; B windows 0,1
  {
    float4 p0[4];
#pragma unroll
    for (int j = 0; j < 4; j++) p0[j] = *(const float4*)(lp + g * 4 + j * 64);
    stageW(p0, 0);
  }
  float4 pA[4];
#pragma unroll
  for (int j = 0; j < 4; j++) pA[j] = *(const float4*)(lp + CK + g * 4 + j * 64);

  bf16x8 bw0[4], bw1[4];
#pragma unroll
  for (int ni = 0; ni < 4; ni++) bw0[ni] = *(const bf16x8*)(Brow[ni]);
#pragma unroll
  for (int ni = 0; ni < 4; ni++) bw1[ni] = *(const bf16x8*)(Brow[ni] + BK);
  __syncthreads();

  for (int c = 0; c < NCH; c++) {
    // issue chunk c+2 E loads (two chunks of compute to cover latency)
    float4 pB_[4] = {};
    if (c + 2 < NCH) {
      const int kbase = (c + 2) * CK;
#pragma unroll
      for (int j = 0; j < 4; j++)
        pB_[j] = *(const float4*)(lp + kbase + g * 4 + j * 64);
    }

    // GEMM this chunk's 8 windows; static bw0/bw1 parity; prefetch 2 ahead
    const unsigned char* buf = wlds[c & 1];
#pragma unroll
    for (int w = 0; w < CK / BK; w += 2) {
      const int gw = c * (CK / BK) + w;
      {
        bf16x8 a0 = *(const bf16x8*)(buf + pv_lds(lrow, (unsigned)(w * 64 + quad * 16)));
        bf16x8 a1 = *(const bf16x8*)(buf + pv_lds(16 + lrow, (unsigned)(w * 64 + quad * 16)));
#pragma unroll
        for (int ni = 0; ni < 4; ni++)
          acc[0][ni] = __builtin_amdgcn_mfma_f32_16x16x32_bf16(a0, bw0[ni], acc[0][ni], 0, 0, 0);
#pragma unroll
        for (int ni = 0; ni < 4; ni++)
          acc[1][ni] = __builtin_amdgcn_mfma_f32_16x16x32_bf16(a1, bw0[ni], acc[1][ni], 0, 0, 0);
        if (gw + 2 < NWIN) {
#pragma unroll
          for (int ni = 0; ni < 4; ni++)
            bw0[ni] = *(const bf16x8*)(Brow[ni] + (gw + 2) * BK);
        }
      }
      {
        bf16x8 a0 = *(const bf16x8*)(buf + pv_lds(lrow, (unsigned)((w + 1) * 64 + quad * 16)));
        bf16x8 a1 = *(const bf16x8*)(buf + pv_lds(16 + lrow, (unsigned)((w + 1) * 64 + quad * 16)));
#pragma unroll
        for (int ni = 0; ni < 4; ni++)
          acc[0][ni] = __builtin_amdgcn_mfma_f32_16x16x32_bf16(a0, bw1[ni], acc[0][ni], 0, 0, 0);
#pragma unroll
        for (int ni = 0; ni < 4; ni++)
          acc[1][ni] = __builtin_amdgcn_mfma_f32_16x16x32_bf16(a1, bw1[ni], acc[1][ni], 0, 0, 0);
        if (gw + 3 < NWIN) {
#pragma unroll
          for (int ni = 0; ni < 4; ni++)
            bw1[ni] = *(const bf16x8*)(Brow[ni] + (gw + 3) * BK);
        }
      }
    }

    if (c + 1 < NCH) {
      stageW(pA, c + 1);  // uses loads issued LAST iteration (fully covered)
      // LDS-visibility-only barrier: global prefetches stay in flight
      asm volatile("s_waitcnt lgkmcnt(0)\n\ts_barrier" ::: "memory");
    }
#pragma unroll
    for (int j = 0; j < 4; j++) pA[j] = pB_[j];
  }

  float* Ob = O + (size_t)b * SQ * DD;
#pragma unroll
  for (int ni = 0; ni < 4; ni++) {
    const int d = wn + ni * 16 + lrow;
#pragma unroll
    for (int mi = 0; mi < 2; mi++) {
      const int mbase = m0 + mi * 16 + quad * 4;
#pragma unroll
      for (int r = 0; r < 4; r++) {
        Ob[(size_t)(mbase + r) * DD + d] = acc[mi][ni][r];
      }
    }
  }
}

extern "C" void kernel_launch(void* const* d_in, const int* in_sizes, int n_in,
                              void* d_out, int out_size, void* d_ws, size_t ws_size,
                              hipStream_t stream) {
  const float* Q = (const float*)d_in[0];
  const float* K = (const float*)d_in[1];
  const float* V = (const float*)d_in[2];
  const float* T = (const float*)d_in[3];

  float* outv = (float*)d_out;                          // [8,2048,512]
  float* logits = outv + (size_t)NB * SQ * DD;          // [8,2048,2048] weights region

  // workspace: partials 2 x [8][32][2048] f32 (4.2 MB) + Vt bf16 (16.8 MB)
  float* Mpart = (float*)d_ws;
  float* Spart = Mpart + (size_t)NB * NG * SQ;
  bf16_t* Vt = (bf16_t*)(Spart + (size_t)NB * NG * SQ);

  vt_kernel<<<dim3(SK / 32, NB), 256, 0, stream>>>(V, Vt);
  logits_kernel<<<dim3(SK / BN, SQ / BM, NB), 256, 0, stream>>>(Q, K, T, logits,
                                                                Mpart, Spart);
  pv_kernel<<<dim3(NB * (SQ / PM)), 512, 0, stream>>>(logits, Vt, Mpart, Spart, outv);
}